// Round 8
// baseline (571.941 us; speedup 1.0000x reference)
//
#include <hip/hip_runtime.h>
#include <hip/hip_bf16.h>
#include <cstdint>

// GroupFNO1d on MI355X. Rows = B*E = 32768.
// Algebra: spectral (64 kept rFFT modes) == analysis GEMM (128 cos/-sin rows) +
// per-(e,k) complex mix + synthesis folded into next weight (K 1024->1152).
// Spectral-1 folded INTO GEMM-1: B-panel = [p_w | G=Fb@p_w], K=512, mix in epilogue.
// Round 8: within-iter fragment double-buffering in gemm256 — issue BOTH kk-half
// fragment reads up front, lgkmcnt(12) -> MFMA kk0 (kk1 reads in flight),
// lgkmcnt(0) -> MFMA kk1. Round-7 falsified fetch-BW theory (FETCH 83->55MB,
// time flat); LDS-read/MFMA serialization is the bottleneck (both ~2 kcyc/iter,
// taking turns). XCD-aware grid decode kept (it is free and halves HBM).

typedef __bf16 bf16;
typedef __attribute__((ext_vector_type(8))) __bf16 bf16x8;
typedef __attribute__((ext_vector_type(4))) __bf16 bf16x4;
typedef __attribute__((ext_vector_type(4))) float f32x4;

#define N_ROWS 32768

__device__ __forceinline__ void gl_lds16(const void* g, void* l) {
    __builtin_amdgcn_global_load_lds(
        (const __attribute__((address_space(1))) void*)g,
        (__attribute__((address_space(3))) void*)l,
        16, 0, 0);
}

__device__ __forceinline__ float swishf(float v) {
    return v / (1.f + __expf(-v));
}

// ---------------- setup kernels ----------------

__global__ __launch_bounds__(256) void build_cmix(const float* __restrict__ codes,
                                                  const float* __restrict__ com,
                                                  const float* __restrict__ code,
                                                  const float* __restrict__ filt,
                                                  float2* __restrict__ cmix) {
    int t = blockIdx.x * 256 + threadIdx.x;
    if (t >= 16 * 64) return;
    int e = t >> 6, m = t & 63;
    float er = 0.f, ei = 0.f;
    for (int c = 0; c < 64; ++c) {
        float cd = codes[e * 64 + c];
        er += cd * code[(c * 64 + m) * 2 + 0];
        ei += cd * code[(c * 64 + m) * 2 + 1];
    }
    float f = filt[m];
    float lam = fminf(fmaxf((f + 3.f) * (1.f / 6.f), 0.f), 1.f);
    float cr = lam * com[m * 2 + 0] + (1.f - lam) * er;
    float ci = lam * com[m * 2 + 1] + (1.f - lam) * ei;
    float g = (m == 0) ? (1.f / 1024.f) : (2.f / 1024.f);
    cmix[t] = make_float2(g * cr, g * ci);
}

__global__ __launch_bounds__(256) void build_fb2(float* __restrict__ Fb32,
                                                 bf16* __restrict__ Fbb) {
    int t = blockIdx.x * 256 + threadIdx.x;   // 131072
    int rr = t >> 10, s = t & 1023;
    int k = rr >> 1;
    int ph = (k * s) & 1023;
    float ang = (float)ph * 6.1359231515425649e-3f;  // 2*pi/1024
    float v = (rr & 1) ? -sinf(ang) : cosf(ang);
    Fb32[t] = v;
    Fbb[t] = (bf16)v;
}

__global__ __launch_bounds__(256) void build_bcat(const float* __restrict__ w,
                                                  bf16* __restrict__ out) {
    int t = blockIdx.x * 256 + threadIdx.x;
    if (t >= 1024 * 1152) return;
    int j = t / 1152, c = t % 1152;
    float v;
    if (c < 1024) {
        v = w[j * 1024 + c];
    } else {
        int cc = c - 1024, k = cc >> 1;
        int ph = (k * j) & 1023;
        float ang = (float)ph * 6.1359231515425649e-3f;
        v = (cc & 1) ? -sinf(ang) : cosf(ang);
    }
    out[t] = (bf16)v;
}

// G32[k2][c] = sum_w Fb32[k2][w] * p_w[w][c], c<512. grid (2,128), coalesced.
__global__ __launch_bounds__(256) void build_g(const float* __restrict__ Fb32,
                                               const float* __restrict__ p_w,
                                               float* __restrict__ G32) {
    int c = blockIdx.x * 256 + threadIdx.x;
    int k2 = blockIdx.y;
    const float* fb = Fb32 + k2 * 1024;
    float a = 0.f;
    #pragma unroll 8
    for (int w = 0; w < 1024; ++w)
        a += fb[w] * p_w[(size_t)w * 1024 + c];
    G32[k2 * 512 + c] = a;
}

// bias1[w] = p_b[w] + sum_s (s/511)*p_w[w][512+s]. One WAVE per w.
__global__ __launch_bounds__(256) void build_bias1a(const float* __restrict__ p_w,
                                                    const float* __restrict__ p_b,
                                                    float* __restrict__ bias1) {
    int w = (blockIdx.x * 256 + threadIdx.x) >> 6;
    int lane = threadIdx.x & 63;
    const float* src = p_w + (size_t)w * 1024 + 512 + lane * 8;
    float4 v0 = *(const float4*)(src);
    float4 v1 = *(const float4*)(src + 4);
    float s0 = (float)(lane * 8) * (1.f / 511.f);
    const float st = 1.f / 511.f;
    float a = v0.x * s0 + v0.y * (s0 + st) + v0.z * (s0 + 2 * st) + v0.w * (s0 + 3 * st)
            + v1.x * (s0 + 4 * st) + v1.y * (s0 + 5 * st) + v1.z * (s0 + 6 * st) + v1.w * (s0 + 7 * st);
    #pragma unroll
    for (int msk = 1; msk < 64; msk <<= 1) a += __shfl_xor(a, msk);
    if (lane == 0) bias1[w] = p_b[w] + a;
}

// bias1[1024+k2] = sum_w Fb32[k2][w]*bias1[w]; zero 1152..1279. One WAVE per k2.
__global__ __launch_bounds__(256) void build_bias1b(const float* __restrict__ Fb32,
                                                    float* __restrict__ bias1) {
    int k2 = blockIdx.x * 4 + (threadIdx.x >> 6);
    int lane = threadIdx.x & 63;
    const float* fb = Fb32 + (size_t)k2 * 1024 + lane * 16;
    const float* bb = bias1 + lane * 16;
    float a = 0.f;
    #pragma unroll
    for (int j = 0; j < 4; ++j) {
        float4 f = *(const float4*)(fb + 4 * j);
        float4 b = *(const float4*)(bb + 4 * j);
        a += f.x * b.x + f.y * b.y + f.z * b.z + f.w * b.w;
    }
    #pragma unroll
    for (int msk = 1; msk < 64; msk <<= 1) a += __shfl_xor(a, msk);
    if (lane == 0) {
        bias1[1024 + k2] = a;
        bias1[1152 + k2] = 0.f;
    }
}

// WP (1280 x 512 bf16): rows<1024 = p_w[r][c]; 1024..1151 = G32; >=1152 = 0
__global__ __launch_bounds__(256) void build_wp(const float* __restrict__ p_w,
                                                const float* __restrict__ G32,
                                                bf16* __restrict__ WP) {
    int t = blockIdx.x * 256 + threadIdx.x;
    if (t >= 1280 * 512) return;
    int r = t >> 9, c = t & 511;
    float v = (r < 1024) ? p_w[(size_t)r * 1024 + c]
            : (r < 1152) ? G32[(r - 1024) * 512 + c] : 0.f;
    WP[t] = (bf16)v;
}

__global__ __launch_bounds__(256) void convert_x(const float* __restrict__ x,
                                                 bf16* __restrict__ A0) {
    int t = blockIdx.x * 256 + threadIdx.x;
    const float4* xp = (const float4*)(x + (size_t)t * 8);
    float4 a = xp[0], b = xp[1];
    bf16x8 o;
    o[0] = (bf16)a.x; o[1] = (bf16)a.y; o[2] = (bf16)a.z; o[3] = (bf16)a.w;
    o[4] = (bf16)b.x; o[5] = (bf16)b.y; o[6] = (bf16)b.z; o[7] = (bf16)b.w;
    *(bf16x8*)(A0 + (size_t)t * 8) = o;
}

// ---------------- big GEMM: 256x256 tile, BK=64, T2 swizzle, XCD grid, ----------
// ---------------- within-iter fragment double-buffer (round 8) ------------------
template<int ACT, int HASMIX>
__global__ __launch_bounds__(512, 2)
void gemm256(const bf16* __restrict__ A, int lda,
             const bf16* __restrict__ Bt, int ldb,
             const float* __restrict__ bias,
             bf16* __restrict__ Cout, int ldc,
             const float2* __restrict__ cmix, int ncols,
             int K, int NX, int NY) {
    __shared__ bf16 sA[2][256 * 64];
    __shared__ bf16 sB[2][256 * 64];
    const int tid = threadIdx.x;
    const int wave = tid >> 6, lane = tid & 63;
    const int wm = wave >> 2, wn = wave & 3;

    int tx, ty;
    if ((NX & 7) == 0) {
        int xcd = blockIdx.x & 7;
        int pos = blockIdx.x >> 3;
        ty = pos % NY;
        tx = (pos / NY) * 8 + xcd;
    } else {
        tx = blockIdx.x % NX;
        ty = blockIdx.x / NX;
    }
    const int rowA0 = tx * 256;
    const int rowB0 = ty * 256;

    f32x4 acc[8][4];
    #pragma unroll
    for (int m = 0; m < 8; ++m)
        #pragma unroll
        for (int n = 0; n < 4; ++n)
            acc[m][n] = f32x4{0.f, 0.f, 0.f, 0.f};

    const int srq = lane >> 3;                 // row within 8-row group
    const int ssl = (lane & 7) ^ srq;          // inverse-swizzled 16B col slot
    const bf16* gA = A + (size_t)(rowA0 + wave * 8 + srq) * lda + ssl * 8;
    const bf16* gB = Bt + (size_t)(rowB0 + wave * 8 + srq) * ldb + ssl * 8;

    const int NT = K / 64;
    auto STAGE = [&](int t) {
        const int slot = t & 1;
        const size_t ko = (size_t)t * 64;
        #pragma unroll
        for (int j = 0; j < 4; ++j) {
            gl_lds16(gA + (size_t)j * 64 * lda + ko, &sA[slot][(j * 64 + wave * 8) * 64]);
            gl_lds16(gB + (size_t)j * 64 * ldb + ko, &sB[slot][(j * 64 + wave * 8) * 64]);
        }
    };

    STAGE(0);

    const int p = lane & 15, q = lane >> 4;
    const int axr = (p & 7) << 4;              // read-side byte XOR

    for (int t = 0; t < NT; ++t) {
        asm volatile("s_waitcnt vmcnt(0)" ::: "memory");
        __builtin_amdgcn_s_barrier();
        __builtin_amdgcn_sched_barrier(0);
        if (t + 1 < NT) STAGE(t + 1);
        const char* sa = (const char*)sA[t & 1];
        const char* sb = (const char*)sB[t & 1];
        // issue ALL fragment reads for both kk halves (kk0 first, then kk1)
        bf16x8 af0[8], bf0[4], af1[8], bf1[4];
        #pragma unroll
        for (int m = 0; m < 8; ++m) {
            int off = (((wm * 128 + m * 16 + p) * 64 + q * 8) * 2) ^ axr;
            af0[m] = *(const bf16x8*)(sa + off);
        }
        #pragma unroll
        for (int n = 0; n < 4; ++n) {
            int off = (((wn * 64 + n * 16 + p) * 64 + q * 8) * 2) ^ axr;
            bf0[n] = *(const bf16x8*)(sb + off);
        }
        #pragma unroll
        for (int m = 0; m < 8; ++m) {
            int off = (((wm * 128 + m * 16 + p) * 64 + 32 + q * 8) * 2) ^ axr;
            af1[m] = *(const bf16x8*)(sa + off);
        }
        #pragma unroll
        for (int n = 0; n < 4; ++n) {
            int off = (((wn * 64 + n * 16 + p) * 64 + 32 + q * 8) * 2) ^ axr;
            bf1[n] = *(const bf16x8*)(sb + off);
        }
        // kk0 done (DS completes in order); kk1's 12 reads still in flight
        asm volatile("s_waitcnt lgkmcnt(12)" ::: "memory");
        __builtin_amdgcn_sched_barrier(0);
        __builtin_amdgcn_s_setprio(1);
        #pragma unroll
        for (int m = 0; m < 8; ++m)
            #pragma unroll
            for (int n = 0; n < 4; ++n)
                acc[m][n] = __builtin_amdgcn_mfma_f32_16x16x32_bf16(af0[m], bf0[n], acc[m][n], 0, 0, 0);
        __builtin_amdgcn_s_setprio(0);
        asm volatile("s_waitcnt lgkmcnt(0)" ::: "memory");
        __builtin_amdgcn_sched_barrier(0);
        __builtin_amdgcn_s_setprio(1);
        #pragma unroll
        for (int m = 0; m < 8; ++m)
            #pragma unroll
            for (int n = 0; n < 4; ++n)
                acc[m][n] = __builtin_amdgcn_mfma_f32_16x16x32_bf16(af1[m], bf1[n], acc[m][n], 0, 0, 0);
        __builtin_amdgcn_s_setprio(0);
        __builtin_amdgcn_sched_barrier(0);
    }

    const int rowb = rowA0 + wm * 128;
    const int colb = rowB0 + wn * 64;
    #pragma unroll
    for (int m = 0; m < 8; ++m) {
        #pragma unroll
        for (int n = 0; n < 4; ++n) {
            int col = colb + n * 16 + p;
            float bv = bias ? bias[col] : 0.f;
            #pragma unroll
            for (int r = 0; r < 4; ++r) {
                int row = rowb + m * 16 + q * 4 + r;
                float v = acc[m][n][r] + bv;
                if (HASMIX) {
                    float pp = __shfl_xor(v, 1);       // partner col (uniform exec)
                    if (col >= 1024) {
                        int k = (col - 1024) >> 1;
                        float2 c = cmix[(row & 15) * 64 + k];
                        v = v * c.x + (((p & 1) == 0) ? -pp * c.y : pp * c.y);
                    }
                    if (col < ncols) Cout[(size_t)row * ldc + col] = (bf16)v;
                } else {
                    if (ACT) v = swishf(v);
                    Cout[(size_t)row * ldc + col] = (bf16)v;
                }
            }
        }
    }
}

// ---------------- 128^2 GEMM for the layer-2 analysis+mix step ----------------
__global__ __launch_bounds__(256)
void gemm_mix(const bf16* __restrict__ A, int lda,
              const bf16* __restrict__ Bt, int ldb,
              void* __restrict__ Cout, int ldc,
              const float2* __restrict__ cmix,
              int K) {
    __shared__ bf16 sA[128 * 64];
    __shared__ bf16 sB[128 * 64];
    const int tid = threadIdx.x;
    const int wave = tid >> 6;
    const int lane = tid & 63;
    const int wm = wave >> 1, wn = wave & 1;
    const int rowA0 = blockIdx.x * 128;

    f32x4 acc[4][4];
    #pragma unroll
    for (int m = 0; m < 4; ++m)
        #pragma unroll
        for (int n = 0; n < 4; ++n)
            acc[m][n] = f32x4{0.f, 0.f, 0.f, 0.f};

    const int srow = wave * 32 + (lane >> 3);
    const int scol = (lane & 7) * 8;
    const bf16* gA = A + (size_t)(rowA0 + srow) * lda + scol;
    const bf16* gB = Bt + (size_t)srow * ldb + scol;
    bf16* lA = &sA[(wave * 32) * 64];
    bf16* lB = &sB[(wave * 32) * 64];

    for (int k0 = 0; k0 < K; k0 += 64) {
        __syncthreads();
        #pragma unroll
        for (int i = 0; i < 4; ++i) {
            gl_lds16(gA + (size_t)i * 8 * lda + k0, lA + i * 8 * 64);
            gl_lds16(gB + (size_t)i * 8 * ldb + k0, lB + i * 8 * 64);
        }
        __syncthreads();
        #pragma unroll
        for (int kk = 0; kk < 64; kk += 32) {
            bf16x8 af[4], bfr[4];
            #pragma unroll
            for (int m = 0; m < 4; ++m)
                af[m] = *(const bf16x8*)&sA[(wm * 64 + m * 16 + (lane & 15)) * 64 + kk + ((lane >> 4) * 8)];
            #pragma unroll
            for (int n = 0; n < 4; ++n)
                bfr[n] = *(const bf16x8*)&sB[(wn * 64 + n * 16 + (lane & 15)) * 64 + kk + ((lane >> 4) * 8)];
            #pragma unroll
            for (int m = 0; m < 4; ++m)
                #pragma unroll
                for (int n = 0; n < 4; ++n)
                    acc[m][n] = __builtin_amdgcn_mfma_f32_16x16x32_bf16(af[m], bfr[n], acc[m][n], 0, 0, 0);
        }
    }

    const int rowb = rowA0 + wm * 64;
    #pragma unroll
    for (int m = 0; m < 4; ++m) {
        #pragma unroll
        for (int n = 0; n < 4; ++n) {
            int col = wn * 64 + n * 16 + (lane & 15);
            int k = col >> 1;
            #pragma unroll
            for (int r = 0; r < 4; ++r) {
                float v = acc[m][n][r];
                float pp = __shfl_xor(v, 1);
                int row = rowb + m * 16 + (lane >> 4) * 4 + r;
                float2 c = cmix[(row & 15) * 64 + k];
                float val = v * c.x + (((lane & 1) == 0) ? -pp * c.y : pp * c.y);
                ((bf16*)Cout)[(size_t)row * ldc + col] = (bf16)val;
            }
        }
    }
}

// ---------------- fused fc1 + swish + fc2 (bf16) ----------------
__global__ __launch_bounds__(256) void fc_fused(const bf16* __restrict__ H,
                                                const float* __restrict__ w1,
                                                const float* __restrict__ b1,
                                                const float* __restrict__ w2,
                                                const float* __restrict__ b2,
                                                float* __restrict__ out) {
    __shared__ bf16 sw2[8][2048];
    __shared__ bf16 ss[2048];
    int tid = threadIdx.x;
    for (int i = tid * 4; i < 8 * 2048; i += 1024) {
        float4 v = *(const float4*)(w2 + i);
        bf16x4 b = {(bf16)v.x, (bf16)v.y, (bf16)v.z, (bf16)v.w};
        *(bf16x4*)&sw2[0][i] = b;
    }

    float wv[16];
    const float4* w1p = (const float4*)(w1 + tid * 16);
    *(float4*)&wv[0]  = w1p[0];
    *(float4*)&wv[4]  = w1p[1];
    *(float4*)&wv[8]  = w1p[2];
    *(float4*)&wv[12] = w1p[3];
    float bb[8];
    const float4* b1p = (const float4*)(b1 + tid * 8);
    *(float4*)&bb[0] = b1p[0];
    *(float4*)&bb[4] = b1p[1];
    __syncthreads();

    for (int r = 0; r < 16; ++r) {
        int n = blockIdx.x * 16 + r;
        bf16x4 hv = *(const bf16x4*)(H + (size_t)n * 1024 + tid * 4);
        float hh[4] = {(float)hv[0], (float)hv[1], (float)hv[2], (float)hv[3]};
        bf16x8 sb;
        #pragma unroll
        for (int jj = 0; jj < 8; ++jj) {
            float h0 = hh[(jj >> 2) * 2];
            float h1 = hh[(jj >> 2) * 2 + 1];
            float t = h0 * wv[2 * jj] + h1 * wv[2 * jj + 1] + bb[jj];
            sb[jj] = (bf16)swishf(t);
        }
        *(bf16x8*)&ss[tid * 8] = sb;
        __syncthreads();
        int o8 = tid >> 5, l5 = tid & 31;
        float p = 0.f;
        #pragma unroll
        for (int i = 0; i < 16; ++i) {
            bf16x4 a = *(const bf16x4*)&ss[4 * l5 + 128 * i];
            bf16x4 b = *(const bf16x4*)&sw2[o8][4 * l5 + 128 * i];
            p += (float)a[0] * (float)b[0] + (float)a[1] * (float)b[1]
               + (float)a[2] * (float)b[2] + (float)a[3] * (float)b[3];
        }
        #pragma unroll
        for (int msk = 1; msk < 32; msk <<= 1) p += __shfl_xor(p, msk);
        if (l5 == 0) out[(size_t)n * 8 + o8] = p + b2[o8];
        __syncthreads();
    }
}

// ---------------- launch ----------------

extern "C" void kernel_launch(void* const* d_in, const int* in_sizes, int n_in,
                              void* d_out, int out_size, void* d_ws, size_t ws_size,
                              hipStream_t stream) {
    const float* x     = (const float*)d_in[0];
    const float* codes = (const float*)d_in[1];
    const float* p_w   = (const float*)d_in[2];
    const float* p_b   = (const float*)d_in[3];
    const float* com0  = (const float*)d_in[4];
    const float* code0 = (const float*)d_in[5];
    const float* filt0 = (const float*)d_in[6];
    const float* com1  = (const float*)d_in[7];
    const float* code1 = (const float*)d_in[8];
    const float* filt1 = (const float*)d_in[9];
    const float* w0_w  = (const float*)d_in[10];
    const float* w0_b  = (const float*)d_in[11];
    const float* w1_w  = (const float*)d_in[12];
    const float* w1_b  = (const float*)d_in[13];
    const float* fc1w  = (const float*)d_in[14];
    const float* fc1b  = (const float*)d_in[15];
    const float* fc2w  = (const float*)d_in[16];
    const float* fc2b  = (const float*)d_in[17];
    float* out = (float*)d_out;

    // fixed weight region (~7.1 MB)
    char* ws = (char*)d_ws;
    bf16*  WP   = (bf16*)(ws + 0);               // 1,310,720
    bf16*  B0   = (bf16*)(ws + 1310720);         // 2,359,296
    bf16*  B1   = (bf16*)(ws + 3670016);         // 2,359,296
    bf16*  Fbb  = (bf16*)(ws + 6029312);         // 262,144
    float* Fb32 = (float*)(ws + 6291456);        // 524,288
    float* G32  = (float*)(ws + 6815744);        // 262,144
    float* bias1= (float*)(ws + 7077888);        // 5,120
    float2* cm0 = (float2*)(ws + 7083008);       // 8,192
    float2* cm1 = (float2*)(ws + 7091200);       // 8,192
    const size_t CB = 7099392;

    const size_t PER_ROW = 2048 + 2304 + 2304;   // 6656
    long rmax = 0;
    if (ws_size > CB) rmax = (long)((ws_size - CB) / PER_ROW) / 256 * 256;
    if (rmax > N_ROWS) rmax = N_ROWS;
    if (rmax < 256) {
        hipMemsetAsync(d_out, 0, (size_t)out_size * sizeof(float), stream);
        return;
    }
    const int R = (int)rmax;

    build_cmix<<<4, 256, 0, stream>>>(codes, com0, code0, filt0, cm0);
    build_cmix<<<4, 256, 0, stream>>>(codes, com1, code1, filt1, cm1);
    build_fb2<<<512, 256, 0, stream>>>(Fb32, Fbb);
    build_bcat<<<4608, 256, 0, stream>>>(w0_w, B0);
    build_bcat<<<4608, 256, 0, stream>>>(w1_w, B1);
    build_g<<<dim3(2, 128), 256, 0, stream>>>(Fb32, p_w, G32);
    build_bias1a<<<256, 256, 0, stream>>>(p_w, p_b, bias1);
    build_bias1b<<<32, 256, 0, stream>>>(Fb32, bias1);
    build_wp<<<2560, 256, 0, stream>>>(p_w, G32, WP);

    char* cb = ws + CB;
    for (int row0 = 0; row0 < N_ROWS; row0 += R) {
        const int r = (N_ROWS - row0 < R) ? (N_ROWS - row0) : R;   // multiple of 256
        bf16*  A0  = (bf16*)cb;
        bf16*  H3b = (bf16*)cb;                                    // reuses A0 region
        bf16*  A1  = (bf16*)(cb + (size_t)R * 2048);
        bf16*  A2  = (bf16*)(cb + (size_t)R * 2048 + (size_t)R * 2304);
        const int NX = r / 256;

        convert_x<<<r / 4, 256, 0, stream>>>(x + (size_t)row0 * 512, A0);

        // A1cat[:,0:1024] = A0@p_w[:, :512]^T + bias1; [:,1024:1152] = mix(A0@G^T + b1B)
        gemm256<0, 1><<<NX * 5, 512, 0, stream>>>(
            A0, 512, WP, 512, bias1, A1, 1152, cm0, 1152, 512, NX, 5);
        // A2cat[:,0:1024] = swish(A1cat @ Bcat0^T + w0_b)
        gemm256<1, 0><<<NX * 4, 512, 0, stream>>>(
            A1, 1152, B0, 1152, w0_b, A2, 1152, nullptr, 1024, 1152, NX, 4);
        // A2cat[:,1024:1152] = mix(A2[:,0:1024] @ Fb^T)
        gemm_mix<<<dim3(r / 128, 1), 256, 0, stream>>>(
            A2, 1152, Fbb, 1024, (void*)(A2 + 1024), 1152, cm1, 1024);
        // H3 = A2cat @ Bcat1^T + w1_b (bf16)
        gemm256<0, 0><<<NX * 4, 512, 0, stream>>>(
            A2, 1152, B1, 1152, w1_b, H3b, 1024, nullptr, 1024, 1152, NX, 4);
        // out = fc2(swish(fc1(H3)))
        fc_fused<<<r / 16, 256, 0, stream>>>(H3b, fc1w, fc1b, fc2w, fc2b, out + (size_t)row0 * 8);
    }
}

// Round 9
// 509.504 us; speedup vs baseline: 1.1225x; 1.1225x over previous
//
#include <hip/hip_runtime.h>
#include <hip/hip_bf16.h>
#include <cstdint>

// GroupFNO1d on MI355X. Rows = B*E = 32768.
// Spectral (64 kept rFFT modes) == analysis GEMM + complex mix + synthesis folded
// into next weight (K 1024->1152). Spectral-1 folded into GEMM-1 (B=[p_w|G], K=512).
// Round 9: gemm256 = BK=32, 4 LDS slots, 2-deep prefetch, counted vmcnt(8)
// (round-3 proven sync structure) + swizzle adapted to 64B rows (slot^=row&3,
// both sides) — the untested "deep prefetch + conflict-free" cell. Round-8's
// fragment dbuf (spilled, -20%) reverted. XCD grid decode kept.

typedef __bf16 bf16;
typedef __attribute__((ext_vector_type(8))) __bf16 bf16x8;
typedef __attribute__((ext_vector_type(4))) __bf16 bf16x4;
typedef __attribute__((ext_vector_type(4))) float f32x4;

#define N_ROWS 32768

__device__ __forceinline__ void gl_lds16(const void* g, void* l) {
    __builtin_amdgcn_global_load_lds(
        (const __attribute__((address_space(1))) void*)g,
        (__attribute__((address_space(3))) void*)l,
        16, 0, 0);
}

__device__ __forceinline__ float swishf(float v) {
    return v / (1.f + __expf(-v));
}

// ---------------- setup kernels ----------------

__global__ __launch_bounds__(256) void build_cmix(const float* __restrict__ codes,
                                                  const float* __restrict__ com,
                                                  const float* __restrict__ code,
                                                  const float* __restrict__ filt,
                                                  float2* __restrict__ cmix) {
    int t = blockIdx.x * 256 + threadIdx.x;
    if (t >= 16 * 64) return;
    int e = t >> 6, m = t & 63;
    float er = 0.f, ei = 0.f;
    for (int c = 0; c < 64; ++c) {
        float cd = codes[e * 64 + c];
        er += cd * code[(c * 64 + m) * 2 + 0];
        ei += cd * code[(c * 64 + m) * 2 + 1];
    }
    float f = filt[m];
    float lam = fminf(fmaxf((f + 3.f) * (1.f / 6.f), 0.f), 1.f);
    float cr = lam * com[m * 2 + 0] + (1.f - lam) * er;
    float ci = lam * com[m * 2 + 1] + (1.f - lam) * ei;
    float g = (m == 0) ? (1.f / 1024.f) : (2.f / 1024.f);
    cmix[t] = make_float2(g * cr, g * ci);
}

__global__ __launch_bounds__(256) void build_fb2(float* __restrict__ Fb32,
                                                 bf16* __restrict__ Fbb) {
    int t = blockIdx.x * 256 + threadIdx.x;   // 131072
    int rr = t >> 10, s = t & 1023;
    int k = rr >> 1;
    int ph = (k * s) & 1023;
    float ang = (float)ph * 6.1359231515425649e-3f;  // 2*pi/1024
    float v = (rr & 1) ? -sinf(ang) : cosf(ang);
    Fb32[t] = v;
    Fbb[t] = (bf16)v;
}

__global__ __launch_bounds__(256) void build_bcat(const float* __restrict__ w,
                                                  bf16* __restrict__ out) {
    int t = blockIdx.x * 256 + threadIdx.x;
    if (t >= 1024 * 1152) return;
    int j = t / 1152, c = t % 1152;
    float v;
    if (c < 1024) {
        v = w[j * 1024 + c];
    } else {
        int cc = c - 1024, k = cc >> 1;
        int ph = (k * j) & 1023;
        float ang = (float)ph * 6.1359231515425649e-3f;
        v = (cc & 1) ? -sinf(ang) : cosf(ang);
    }
    out[t] = (bf16)v;
}

// G32[k2][c] = sum_w Fb32[k2][w] * p_w[w][c], c<512. grid (2,128), coalesced.
__global__ __launch_bounds__(256) void build_g(const float* __restrict__ Fb32,
                                               const float* __restrict__ p_w,
                                               float* __restrict__ G32) {
    int c = blockIdx.x * 256 + threadIdx.x;
    int k2 = blockIdx.y;
    const float* fb = Fb32 + k2 * 1024;
    float a = 0.f;
    #pragma unroll 8
    for (int w = 0; w < 1024; ++w)
        a += fb[w] * p_w[(size_t)w * 1024 + c];
    G32[k2 * 512 + c] = a;
}

// bias1[w] = p_b[w] + sum_s (s/511)*p_w[w][512+s]. One WAVE per w.
__global__ __launch_bounds__(256) void build_bias1a(const float* __restrict__ p_w,
                                                    const float* __restrict__ p_b,
                                                    float* __restrict__ bias1) {
    int w = (blockIdx.x * 256 + threadIdx.x) >> 6;
    int lane = threadIdx.x & 63;
    const float* src = p_w + (size_t)w * 1024 + 512 + lane * 8;
    float4 v0 = *(const float4*)(src);
    float4 v1 = *(const float4*)(src + 4);
    float s0 = (float)(lane * 8) * (1.f / 511.f);
    const float st = 1.f / 511.f;
    float a = v0.x * s0 + v0.y * (s0 + st) + v0.z * (s0 + 2 * st) + v0.w * (s0 + 3 * st)
            + v1.x * (s0 + 4 * st) + v1.y * (s0 + 5 * st) + v1.z * (s0 + 6 * st) + v1.w * (s0 + 7 * st);
    #pragma unroll
    for (int msk = 1; msk < 64; msk <<= 1) a += __shfl_xor(a, msk);
    if (lane == 0) bias1[w] = p_b[w] + a;
}

// bias1[1024+k2] = sum_w Fb32[k2][w]*bias1[w]; zero 1152..1279. One WAVE per k2.
__global__ __launch_bounds__(256) void build_bias1b(const float* __restrict__ Fb32,
                                                    float* __restrict__ bias1) {
    int k2 = blockIdx.x * 4 + (threadIdx.x >> 6);
    int lane = threadIdx.x & 63;
    const float* fb = Fb32 + (size_t)k2 * 1024 + lane * 16;
    const float* bb = bias1 + lane * 16;
    float a = 0.f;
    #pragma unroll
    for (int j = 0; j < 4; ++j) {
        float4 f = *(const float4*)(fb + 4 * j);
        float4 b = *(const float4*)(bb + 4 * j);
        a += f.x * b.x + f.y * b.y + f.z * b.z + f.w * b.w;
    }
    #pragma unroll
    for (int msk = 1; msk < 64; msk <<= 1) a += __shfl_xor(a, msk);
    if (lane == 0) {
        bias1[1024 + k2] = a;
        bias1[1152 + k2] = 0.f;
    }
}

// WP (1280 x 512 bf16): rows<1024 = p_w[r][c]; 1024..1151 = G32; >=1152 = 0
__global__ __launch_bounds__(256) void build_wp(const float* __restrict__ p_w,
                                                const float* __restrict__ G32,
                                                bf16* __restrict__ WP) {
    int t = blockIdx.x * 256 + threadIdx.x;
    if (t >= 1280 * 512) return;
    int r = t >> 9, c = t & 511;
    float v = (r < 1024) ? p_w[(size_t)r * 1024 + c]
            : (r < 1152) ? G32[(r - 1024) * 512 + c] : 0.f;
    WP[t] = (bf16)v;
}

__global__ __launch_bounds__(256) void convert_x(const float* __restrict__ x,
                                                 bf16* __restrict__ A0) {
    int t = blockIdx.x * 256 + threadIdx.x;
    const float4* xp = (const float4*)(x + (size_t)t * 8);
    float4 a = xp[0], b = xp[1];
    bf16x8 o;
    o[0] = (bf16)a.x; o[1] = (bf16)a.y; o[2] = (bf16)a.z; o[3] = (bf16)a.w;
    o[4] = (bf16)b.x; o[5] = (bf16)b.y; o[6] = (bf16)b.z; o[7] = (bf16)b.w;
    *(bf16x8*)(A0 + (size_t)t * 8) = o;
}

// ------- big GEMM: 256x256, BK=32, 4-slot LDS, 2-deep prefetch, counted vmcnt ------
// Swizzle (64B rows): staging lane l -> row l>>2, slot (l&3)^((l>>2)&3) on the
// GLOBAL side (LDS dest linear); reads XOR byte ((p&3)<<4); frag row&3 == p&3.
// Per iter t: STAGE(t+2) -> vmcnt(8) [waits STAGE(t) complete; t+1,t+2 in flight]
// -> barrier -> 12 frag reads -> lgkmcnt(0) -> 32 MFMA. Slot (t+2)&3 last read at
// iter t-2, ordered by barrier(t-1) -> race-free (round-3 proven structure).
template<int ACT, int HASMIX>
__global__ __launch_bounds__(512, 2)
void gemm256(const bf16* __restrict__ A, int lda,
             const bf16* __restrict__ Bt, int ldb,
             const float* __restrict__ bias,
             bf16* __restrict__ Cout, int ldc,
             const float2* __restrict__ cmix, int ncols,
             int K, int NX, int NY) {
    __shared__ bf16 sA[4][256 * 32];
    __shared__ bf16 sB[4][256 * 32];
    const int tid = threadIdx.x;
    const int wave = tid >> 6, lane = tid & 63;
    const int wm = wave >> 2, wn = wave & 3;

    int tx, ty;
    if ((NX & 7) == 0) {
        int xcd = blockIdx.x & 7;
        int pos = blockIdx.x >> 3;
        ty = pos % NY;
        tx = (pos / NY) * 8 + xcd;
    } else {
        tx = blockIdx.x % NX;
        ty = blockIdx.x / NX;
    }
    const int rowA0 = tx * 256;
    const int rowB0 = ty * 256;

    f32x4 acc[8][4];
    #pragma unroll
    for (int m = 0; m < 8; ++m)
        #pragma unroll
        for (int n = 0; n < 4; ++n)
            acc[m][n] = f32x4{0.f, 0.f, 0.f, 0.f};

    const int srq = lane >> 2;                  // 0..15 row within 16-row group
    const int ssl = (lane & 3) ^ (srq & 3);     // inverse-swizzled 16B slot
    const bf16* gA = A + (size_t)(rowA0 + wave * 16 + srq) * lda + ssl * 8;
    const bf16* gB = Bt + (size_t)(rowB0 + wave * 16 + srq) * ldb + ssl * 8;

    const int NT = K / 32;
    auto STAGE = [&](int t) {
        const int slot = t & 3;
        const size_t ko = (size_t)t * 32;
        gl_lds16(gA + ko,                       &sA[slot][(wave * 16) * 32]);
        gl_lds16(gA + (size_t)128 * lda + ko,   &sA[slot][(128 + wave * 16) * 32]);
        gl_lds16(gB + ko,                       &sB[slot][(wave * 16) * 32]);
        gl_lds16(gB + (size_t)128 * ldb + ko,   &sB[slot][(128 + wave * 16) * 32]);
    };

    STAGE(0);
    STAGE(1);

    const int p = lane & 15, q = lane >> 4;
    const int axr = (p & 3) << 4;              // read-side byte XOR (64B rows)

    for (int t = 0; t < NT; ++t) {
        if (t + 2 < NT) STAGE(t + 2);
        if (t < NT - 2)       { asm volatile("s_waitcnt vmcnt(8)" ::: "memory"); }
        else if (t == NT - 2) { asm volatile("s_waitcnt vmcnt(4)" ::: "memory"); }
        else                  { asm volatile("s_waitcnt vmcnt(0)" ::: "memory"); }
        __builtin_amdgcn_s_barrier();
        __builtin_amdgcn_sched_barrier(0);
        const char* sa = (const char*)sA[t & 3];
        const char* sb = (const char*)sB[t & 3];
        bf16x8 af[8], bfr[4];
        #pragma unroll
        for (int m = 0; m < 8; ++m) {
            int off = (((wm * 128 + m * 16 + p) * 32 + q * 8) * 2) ^ axr;
            af[m] = *(const bf16x8*)(sa + off);
        }
        #pragma unroll
        for (int n = 0; n < 4; ++n) {
            int off = (((wn * 64 + n * 16 + p) * 32 + q * 8) * 2) ^ axr;
            bfr[n] = *(const bf16x8*)(sb + off);
        }
        asm volatile("s_waitcnt lgkmcnt(0)" ::: "memory");
        __builtin_amdgcn_sched_barrier(0);
        __builtin_amdgcn_s_setprio(1);
        #pragma unroll
        for (int m = 0; m < 8; ++m)
            #pragma unroll
            for (int n = 0; n < 4; ++n)
                acc[m][n] = __builtin_amdgcn_mfma_f32_16x16x32_bf16(af[m], bfr[n], acc[m][n], 0, 0, 0);
        __builtin_amdgcn_s_setprio(0);
        __builtin_amdgcn_sched_barrier(0);
    }

    const int rowb = rowA0 + wm * 128;
    const int colb = rowB0 + wn * 64;
    #pragma unroll
    for (int m = 0; m < 8; ++m) {
        #pragma unroll
        for (int n = 0; n < 4; ++n) {
            int col = colb + n * 16 + p;
            float bv = bias ? bias[col] : 0.f;
            #pragma unroll
            for (int r = 0; r < 4; ++r) {
                int row = rowb + m * 16 + q * 4 + r;
                float v = acc[m][n][r] + bv;
                if (HASMIX) {
                    float pp = __shfl_xor(v, 1);       // partner col (uniform exec)
                    if (col >= 1024) {
                        int k = (col - 1024) >> 1;
                        float2 c = cmix[(row & 15) * 64 + k];
                        v = v * c.x + (((p & 1) == 0) ? -pp * c.y : pp * c.y);
                    }
                    if (col < ncols) Cout[(size_t)row * ldc + col] = (bf16)v;
                } else {
                    if (ACT) v = swishf(v);
                    Cout[(size_t)row * ldc + col] = (bf16)v;
                }
            }
        }
    }
}

// ---------------- 128^2 GEMM for the layer-2 analysis+mix step ----------------
__global__ __launch_bounds__(256)
void gemm_mix(const bf16* __restrict__ A, int lda,
              const bf16* __restrict__ Bt, int ldb,
              void* __restrict__ Cout, int ldc,
              const float2* __restrict__ cmix,
              int K) {
    __shared__ bf16 sA[128 * 64];
    __shared__ bf16 sB[128 * 64];
    const int tid = threadIdx.x;
    const int wave = tid >> 6;
    const int lane = tid & 63;
    const int wm = wave >> 1, wn = wave & 1;
    const int rowA0 = blockIdx.x * 128;

    f32x4 acc[4][4];
    #pragma unroll
    for (int m = 0; m < 4; ++m)
        #pragma unroll
        for (int n = 0; n < 4; ++n)
            acc[m][n] = f32x4{0.f, 0.f, 0.f, 0.f};

    const int srow = wave * 32 + (lane >> 3);
    const int scol = (lane & 7) * 8;
    const bf16* gA = A + (size_t)(rowA0 + srow) * lda + scol;
    const bf16* gB = Bt + (size_t)srow * ldb + scol;
    bf16* lA = &sA[(wave * 32) * 64];
    bf16* lB = &sB[(wave * 32) * 64];

    for (int k0 = 0; k0 < K; k0 += 64) {
        __syncthreads();
        #pragma unroll
        for (int i = 0; i < 4; ++i) {
            gl_lds16(gA + (size_t)i * 8 * lda + k0, lA + i * 8 * 64);
            gl_lds16(gB + (size_t)i * 8 * ldb + k0, lB + i * 8 * 64);
        }
        __syncthreads();
        #pragma unroll
        for (int kk = 0; kk < 64; kk += 32) {
            bf16x8 af[4], bfr[4];
            #pragma unroll
            for (int m = 0; m < 4; ++m)
                af[m] = *(const bf16x8*)&sA[(wm * 64 + m * 16 + (lane & 15)) * 64 + kk + ((lane >> 4) * 8)];
            #pragma unroll
            for (int n = 0; n < 4; ++n)
                bfr[n] = *(const bf16x8*)&sB[(wn * 64 + n * 16 + (lane & 15)) * 64 + kk + ((lane >> 4) * 8)];
            #pragma unroll
            for (int m = 0; m < 4; ++m)
                #pragma unroll
                for (int n = 0; n < 4; ++n)
                    acc[m][n] = __builtin_amdgcn_mfma_f32_16x16x32_bf16(af[m], bfr[n], acc[m][n], 0, 0, 0);
        }
    }

    const int rowb = rowA0 + wm * 64;
    #pragma unroll
    for (int m = 0; m < 4; ++m) {
        #pragma unroll
        for (int n = 0; n < 4; ++n) {
            int col = wn * 64 + n * 16 + (lane & 15);
            int k = col >> 1;
            #pragma unroll
            for (int r = 0; r < 4; ++r) {
                float v = acc[m][n][r];
                float pp = __shfl_xor(v, 1);
                int row = rowb + m * 16 + (lane >> 4) * 4 + r;
                float2 c = cmix[(row & 15) * 64 + k];
                float val = v * c.x + (((lane & 1) == 0) ? -pp * c.y : pp * c.y);
                ((bf16*)Cout)[(size_t)row * ldc + col] = (bf16)val;
            }
        }
    }
}

// ---------------- fused fc1 + swish + fc2 (bf16) ----------------
__global__ __launch_bounds__(256) void fc_fused(const bf16* __restrict__ H,
                                                const float* __restrict__ w1,
                                                const float* __restrict__ b1,
                                                const float* __restrict__ w2,
                                                const float* __restrict__ b2,
                                                float* __restrict__ out) {
    __shared__ bf16 sw2[8][2048];
    __shared__ bf16 ss[2048];
    int tid = threadIdx.x;
    for (int i = tid * 4; i < 8 * 2048; i += 1024) {
        float4 v = *(const float4*)(w2 + i);
        bf16x4 b = {(bf16)v.x, (bf16)v.y, (bf16)v.z, (bf16)v.w};
        *(bf16x4*)&sw2[0][i] = b;
    }

    float wv[16];
    const float4* w1p = (const float4*)(w1 + tid * 16);
    *(float4*)&wv[0]  = w1p[0];
    *(float4*)&wv[4]  = w1p[1];
    *(float4*)&wv[8]  = w1p[2];
    *(float4*)&wv[12] = w1p[3];
    float bb[8];
    const float4* b1p = (const float4*)(b1 + tid * 8);
    *(float4*)&bb[0] = b1p[0];
    *(float4*)&bb[4] = b1p[1];
    __syncthreads();

    for (int r = 0; r < 16; ++r) {
        int n = blockIdx.x * 16 + r;
        bf16x4 hv = *(const bf16x4*)(H + (size_t)n * 1024 + tid * 4);
        float hh[4] = {(float)hv[0], (float)hv[1], (float)hv[2], (float)hv[3]};
        bf16x8 sb;
        #pragma unroll
        for (int jj = 0; jj < 8; ++jj) {
            float h0 = hh[(jj >> 2) * 2];
            float h1 = hh[(jj >> 2) * 2 + 1];
            float t = h0 * wv[2 * jj] + h1 * wv[2 * jj + 1] + bb[jj];
            sb[jj] = (bf16)swishf(t);
        }
        *(bf16x8*)&ss[tid * 8] = sb;
        __syncthreads();
        int o8 = tid >> 5, l5 = tid & 31;
        float p = 0.f;
        #pragma unroll
        for (int i = 0; i < 16; ++i) {
            bf16x4 a = *(const bf16x4*)&ss[4 * l5 + 128 * i];
            bf16x4 b = *(const bf16x4*)&sw2[o8][4 * l5 + 128 * i];
            p += (float)a[0] * (float)b[0] + (float)a[1] * (float)b[1]
               + (float)a[2] * (float)b[2] + (float)a[3] * (float)b[3];
        }
        #pragma unroll
        for (int msk = 1; msk < 32; msk <<= 1) p += __shfl_xor(p, msk);
        if (l5 == 0) out[(size_t)n * 8 + o8] = p + b2[o8];
        __syncthreads();
    }
}

// ---------------- launch ----------------

extern "C" void kernel_launch(void* const* d_in, const int* in_sizes, int n_in,
                              void* d_out, int out_size, void* d_ws, size_t ws_size,
                              hipStream_t stream) {
    const float* x     = (const float*)d_in[0];
    const float* codes = (const float*)d_in[1];
    const float* p_w   = (const float*)d_in[2];
    const float* p_b   = (const float*)d_in[3];
    const float* com0  = (const float*)d_in[4];
    const float* code0 = (const float*)d_in[5];
    const float* filt0 = (const float*)d_in[6];
    const float* com1  = (const float*)d_in[7];
    const float* code1 = (const float*)d_in[8];
    const float* filt1 = (const float*)d_in[9];
    const float* w0_w  = (const float*)d_in[10];
    const float* w0_b  = (const float*)d_in[11];
    const float* w1_w  = (const float*)d_in[12];
    const float* w1_b  = (const float*)d_in[13];
    const float* fc1w  = (const float*)d_in[14];
    const float* fc1b  = (const float*)d_in[15];
    const float* fc2w  = (const float*)d_in[16];
    const float* fc2b  = (const float*)d_in[17];
    float* out = (float*)d_out;

    // fixed weight region (~7.1 MB)
    char* ws = (char*)d_ws;
    bf16*  WP   = (bf16*)(ws + 0);               // 1,310,720
    bf16*  B0   = (bf16*)(ws + 1310720);         // 2,359,296
    bf16*  B1   = (bf16*)(ws + 3670016);         // 2,359,296
    bf16*  Fbb  = (bf16*)(ws + 6029312);         // 262,144
    float* Fb32 = (float*)(ws + 6291456);        // 524,288
    float* G32  = (float*)(ws + 6815744);        // 262,144
    float* bias1= (float*)(ws + 7077888);        // 5,120
    float2* cm0 = (float2*)(ws + 7083008);       // 8,192
    float2* cm1 = (float2*)(ws + 7091200);       // 8,192
    const size_t CB = 7099392;

    const size_t PER_ROW = 2048 + 2304 + 2304;   // 6656
    long rmax = 0;
    if (ws_size > CB) rmax = (long)((ws_size - CB) / PER_ROW) / 256 * 256;
    if (rmax > N_ROWS) rmax = N_ROWS;
    if (rmax < 256) {
        hipMemsetAsync(d_out, 0, (size_t)out_size * sizeof(float), stream);
        return;
    }
    const int R = (int)rmax;

    build_cmix<<<4, 256, 0, stream>>>(codes, com0, code0, filt0, cm0);
    build_cmix<<<4, 256, 0, stream>>>(codes, com1, code1, filt1, cm1);
    build_fb2<<<512, 256, 0, stream>>>(Fb32, Fbb);
    build_bcat<<<4608, 256, 0, stream>>>(w0_w, B0);
    build_bcat<<<4608, 256, 0, stream>>>(w1_w, B1);
    build_g<<<dim3(2, 128), 256, 0, stream>>>(Fb32, p_w, G32);
    build_bias1a<<<256, 256, 0, stream>>>(p_w, p_b, bias1);
    build_bias1b<<<32, 256, 0, stream>>>(Fb32, bias1);
    build_wp<<<2560, 256, 0, stream>>>(p_w, G32, WP);

    char* cb = ws + CB;
    for (int row0 = 0; row0 < N_ROWS; row0 += R) {
        const int r = (N_ROWS - row0 < R) ? (N_ROWS - row0) : R;   // multiple of 256
        bf16*  A0  = (bf16*)cb;
        bf16*  H3b = (bf16*)cb;                                    // reuses A0 region
        bf16*  A1  = (bf16*)(cb + (size_t)R * 2048);
        bf16*  A2  = (bf16*)(cb + (size_t)R * 2048 + (size_t)R * 2304);
        const int NX = r / 256;

        convert_x<<<r / 4, 256, 0, stream>>>(x + (size_t)row0 * 512, A0);

        // A1cat[:,0:1024] = A0@p_w[:, :512]^T + bias1; [:,1024:1152] = mix(A0@G^T + b1B)
        gemm256<0, 1><<<NX * 5, 512, 0, stream>>>(
            A0, 512, WP, 512, bias1, A1, 1152, cm0, 1152, 512, NX, 5);
        // A2cat[:,0:1024] = swish(A1cat @ Bcat0^T + w0_b)
        gemm256<1, 0><<<NX * 4, 512, 0, stream>>>(
            A1, 1152, B0, 1152, w0_b, A2, 1152, nullptr, 1024, 1152, NX, 4);
        // A2cat[:,1024:1152] = mix(A2[:,0:1024] @ Fb^T)
        gemm_mix<<<dim3(r / 128, 1), 256, 0, stream>>>(
            A2, 1152, Fbb, 1024, (void*)(A2 + 1024), 1152, cm1, 1024);
        // H3 = A2cat @ Bcat1^T + w1_b (bf16)
        gemm256<0, 0><<<NX * 4, 512, 0, stream>>>(
            A2, 1152, B1, 1152, w1_b, H3b, 1024, nullptr, 1024, 1152, NX, 4);
        // out = fc2(swish(fc1(H3)))
        fc_fused<<<r / 16, 256, 0, stream>>>(H3b, fc1w, fc1b, fc2w, fc2b, out + (size_t)row0 * 8);
    }
}

// Round 10
// 509.005 us; speedup vs baseline: 1.1236x; 1.0010x over previous
//
#include <hip/hip_runtime.h>
#include <hip/hip_bf16.h>
#include <cstdint>

// GroupFNO1d on MI355X. Rows = B*E = 32768.
// Spectral (64 kept rFFT modes) == analysis GEMM + complex mix + synthesis folded
// into next weight (K 1024->1152). Spectral-1 folded into GEMM-1 (B=[p_w|G], K=512).
// Round 10: gemm256 keeps R9's shell (BK=32, 4 slots, 2-deep prefetch, counted
// vmcnt, 1 barrier/tile) and adds (a) intra-wave read/MFMA pipelining with counted
// lgkmcnt (every ds_read issues under an MFMA cluster; 2 tiles per loop iter,
// ping-pong frag sets), (b) corrected 2-way swizzle for 64B rows (R9's was 8-way:
// 7.1M conflicts). Slot discipline: reads touch slots t,t+1; writes t+2,t+3.

typedef __bf16 bf16;
typedef __attribute__((ext_vector_type(8))) __bf16 bf16x8;
typedef __attribute__((ext_vector_type(4))) __bf16 bf16x4;
typedef __attribute__((ext_vector_type(4))) float f32x4;

#define N_ROWS 32768

__device__ __forceinline__ void gl_lds16(const void* g, void* l) {
    __builtin_amdgcn_global_load_lds(
        (const __attribute__((address_space(1))) void*)g,
        (__attribute__((address_space(3))) void*)l,
        16, 0, 0);
}

__device__ __forceinline__ float swishf(float v) {
    return v / (1.f + __expf(-v));
}

// ---------------- setup kernels ----------------

__global__ __launch_bounds__(256) void build_cmix(const float* __restrict__ codes,
                                                  const float* __restrict__ com,
                                                  const float* __restrict__ code,
                                                  const float* __restrict__ filt,
                                                  float2* __restrict__ cmix) {
    int t = blockIdx.x * 256 + threadIdx.x;
    if (t >= 16 * 64) return;
    int e = t >> 6, m = t & 63;
    float er = 0.f, ei = 0.f;
    for (int c = 0; c < 64; ++c) {
        float cd = codes[e * 64 + c];
        er += cd * code[(c * 64 + m) * 2 + 0];
        ei += cd * code[(c * 64 + m) * 2 + 1];
    }
    float f = filt[m];
    float lam = fminf(fmaxf((f + 3.f) * (1.f / 6.f), 0.f), 1.f);
    float cr = lam * com[m * 2 + 0] + (1.f - lam) * er;
    float ci = lam * com[m * 2 + 1] + (1.f - lam) * ei;
    float g = (m == 0) ? (1.f / 1024.f) : (2.f / 1024.f);
    cmix[t] = make_float2(g * cr, g * ci);
}

__global__ __launch_bounds__(256) void build_fb2(float* __restrict__ Fb32,
                                                 bf16* __restrict__ Fbb) {
    int t = blockIdx.x * 256 + threadIdx.x;   // 131072
    int rr = t >> 10, s = t & 1023;
    int k = rr >> 1;
    int ph = (k * s) & 1023;
    float ang = (float)ph * 6.1359231515425649e-3f;  // 2*pi/1024
    float v = (rr & 1) ? -sinf(ang) : cosf(ang);
    Fb32[t] = v;
    Fbb[t] = (bf16)v;
}

__global__ __launch_bounds__(256) void build_bcat(const float* __restrict__ w,
                                                  bf16* __restrict__ out) {
    int t = blockIdx.x * 256 + threadIdx.x;
    if (t >= 1024 * 1152) return;
    int j = t / 1152, c = t % 1152;
    float v;
    if (c < 1024) {
        v = w[j * 1024 + c];
    } else {
        int cc = c - 1024, k = cc >> 1;
        int ph = (k * j) & 1023;
        float ang = (float)ph * 6.1359231515425649e-3f;
        v = (cc & 1) ? -sinf(ang) : cosf(ang);
    }
    out[t] = (bf16)v;
}

// G32[k2][c] = sum_w Fb32[k2][w] * p_w[w][c], c<512. grid (2,128), coalesced.
__global__ __launch_bounds__(256) void build_g(const float* __restrict__ Fb32,
                                               const float* __restrict__ p_w,
                                               float* __restrict__ G32) {
    int c = blockIdx.x * 256 + threadIdx.x;
    int k2 = blockIdx.y;
    const float* fb = Fb32 + k2 * 1024;
    float a = 0.f;
    #pragma unroll 8
    for (int w = 0; w < 1024; ++w)
        a += fb[w] * p_w[(size_t)w * 1024 + c];
    G32[k2 * 512 + c] = a;
}

// bias1[w] = p_b[w] + sum_s (s/511)*p_w[w][512+s]. One WAVE per w.
__global__ __launch_bounds__(256) void build_bias1a(const float* __restrict__ p_w,
                                                    const float* __restrict__ p_b,
                                                    float* __restrict__ bias1) {
    int w = (blockIdx.x * 256 + threadIdx.x) >> 6;
    int lane = threadIdx.x & 63;
    const float* src = p_w + (size_t)w * 1024 + 512 + lane * 8;
    float4 v0 = *(const float4*)(src);
    float4 v1 = *(const float4*)(src + 4);
    float s0 = (float)(lane * 8) * (1.f / 511.f);
    const float st = 1.f / 511.f;
    float a = v0.x * s0 + v0.y * (s0 + st) + v0.z * (s0 + 2 * st) + v0.w * (s0 + 3 * st)
            + v1.x * (s0 + 4 * st) + v1.y * (s0 + 5 * st) + v1.z * (s0 + 6 * st) + v1.w * (s0 + 7 * st);
    #pragma unroll
    for (int msk = 1; msk < 64; msk <<= 1) a += __shfl_xor(a, msk);
    if (lane == 0) bias1[w] = p_b[w] + a;
}

// bias1[1024+k2] = sum_w Fb32[k2][w]*bias1[w]; zero 1152..1279. One WAVE per k2.
__global__ __launch_bounds__(256) void build_bias1b(const float* __restrict__ Fb32,
                                                    float* __restrict__ bias1) {
    int k2 = blockIdx.x * 4 + (threadIdx.x >> 6);
    int lane = threadIdx.x & 63;
    const float* fb = Fb32 + (size_t)k2 * 1024 + lane * 16;
    const float* bb = bias1 + lane * 16;
    float a = 0.f;
    #pragma unroll
    for (int j = 0; j < 4; ++j) {
        float4 f = *(const float4*)(fb + 4 * j);
        float4 b = *(const float4*)(bb + 4 * j);
        a += f.x * b.x + f.y * b.y + f.z * b.z + f.w * b.w;
    }
    #pragma unroll
    for (int msk = 1; msk < 64; msk <<= 1) a += __shfl_xor(a, msk);
    if (lane == 0) {
        bias1[1024 + k2] = a;
        bias1[1152 + k2] = 0.f;
    }
}

// WP (1280 x 512 bf16): rows<1024 = p_w[r][c]; 1024..1151 = G32; >=1152 = 0
__global__ __launch_bounds__(256) void build_wp(const float* __restrict__ p_w,
                                                const float* __restrict__ G32,
                                                bf16* __restrict__ WP) {
    int t = blockIdx.x * 256 + threadIdx.x;
    if (t >= 1280 * 512) return;
    int r = t >> 9, c = t & 511;
    float v = (r < 1024) ? p_w[(size_t)r * 1024 + c]
            : (r < 1152) ? G32[(r - 1024) * 512 + c] : 0.f;
    WP[t] = (bf16)v;
}

__global__ __launch_bounds__(256) void convert_x(const float* __restrict__ x,
                                                 bf16* __restrict__ A0) {
    int t = blockIdx.x * 256 + threadIdx.x;
    const float4* xp = (const float4*)(x + (size_t)t * 8);
    float4 a = xp[0], b = xp[1];
    bf16x8 o;
    o[0] = (bf16)a.x; o[1] = (bf16)a.y; o[2] = (bf16)a.z; o[3] = (bf16)a.w;
    o[4] = (bf16)b.x; o[5] = (bf16)b.y; o[6] = (bf16)b.z; o[7] = (bf16)b.w;
    *(bf16x8*)(A0 + (size_t)t * 8) = o;
}

// ------- big GEMM: 256x256, BK=32, 4-slot LDS, 2-deep prefetch, pipelined reads ----
// Swizzle (64B rows, 2-way/free): LDS(row, slot16B s) holds global(row, s^((row>>1)&3));
// stage: lane l global slot = (l&3)^((l>>3)&3), LDS dest linear; read XOR ((p>>1)&3)<<4.
// Loop processes 2 tiles/iter (ping-pong frag sets x/y). Per tile: read a47(slot t) ->
// lgkm(4) [C0(t), read last tile, confirmed; a47 in flight under M0] -> M0 -> lgkm(0)
// -> issue C0(t+1) (slot t+1; landed: vmcnt(4)@top confirmed tile t+1 + barrier) ->
// M1 overlaps those 8 reads. Writes target slots t+2/t+3 only -> no read/write overlap.
template<int ACT, int HASMIX>
__global__ __launch_bounds__(512, 2)
void gemm256(const bf16* __restrict__ A, int lda,
             const bf16* __restrict__ Bt, int ldb,
             const float* __restrict__ bias,
             bf16* __restrict__ Cout, int ldc,
             const float2* __restrict__ cmix, int ncols,
             int K, int NX, int NY) {
    __shared__ bf16 sA[4][256 * 32];
    __shared__ bf16 sB[4][256 * 32];
    const int tid = threadIdx.x;
    const int wave = tid >> 6, lane = tid & 63;
    const int wm = wave >> 2, wn = wave & 3;

    int tx, ty;
    if ((NX & 7) == 0) {
        int xcd = blockIdx.x & 7;
        int pos = blockIdx.x >> 3;
        ty = pos % NY;
        tx = (pos / NY) * 8 + xcd;
    } else {
        tx = blockIdx.x % NX;
        ty = blockIdx.x / NX;
    }
    const int rowA0 = tx * 256;
    const int rowB0 = ty * 256;

    f32x4 acc[8][4];
    #pragma unroll
    for (int m = 0; m < 8; ++m)
        #pragma unroll
        for (int n = 0; n < 4; ++n)
            acc[m][n] = f32x4{0.f, 0.f, 0.f, 0.f};

    const int srq = lane >> 2;                       // 0..15 row within 16-row group
    const int ssl = (lane & 3) ^ ((lane >> 3) & 3);  // inverse-swizzled 16B slot
    const bf16* gA = A + (size_t)(rowA0 + wave * 16 + srq) * lda + ssl * 8;
    const bf16* gB = Bt + (size_t)(rowB0 + wave * 16 + srq) * ldb + ssl * 8;

    const int NT = K / 32;                           // even for K=512/1024/1152
    auto STAGE = [&](int t) {
        const int slot = t & 3;
        const size_t ko = (size_t)t * 32;
        gl_lds16(gA + ko,                     &sA[slot][(wave * 16) * 32]);
        gl_lds16(gA + (size_t)128 * lda + ko, &sA[slot][(128 + wave * 16) * 32]);
        gl_lds16(gB + ko,                     &sB[slot][(wave * 16) * 32]);
        gl_lds16(gB + (size_t)128 * ldb + ko, &sB[slot][(128 + wave * 16) * 32]);
    };

    const int p = lane & 15, q = lane >> 4;
    const int axr = ((p >> 1) & 3) << 4;             // read-side byte XOR (2-way)

    bf16x8 a03x[4], bfx[4], a03y[4], bfy[4], a47[4];

    // prologue: stage tiles 0,1; confirm tile 0; read C0(0) into x-set
    STAGE(0);
    STAGE(1);
    asm volatile("s_waitcnt vmcnt(4)" ::: "memory");
    __builtin_amdgcn_s_barrier();
    __builtin_amdgcn_sched_barrier(0);
    {
        const char* sa = (const char*)sA[0];
        const char* sb = (const char*)sB[0];
        #pragma unroll
        for (int n = 0; n < 4; ++n)
            bfx[n] = *(const bf16x8*)(sb + ((((wn * 64 + n * 16 + p) * 32 + q * 8) * 2) ^ axr));
        #pragma unroll
        for (int m = 0; m < 4; ++m)
            a03x[m] = *(const bf16x8*)(sa + ((((wm * 128 + m * 16 + p) * 32 + q * 8) * 2) ^ axr));
    }
    __builtin_amdgcn_sched_barrier(0);

    #define TILE_BODY(T, CF_A03, CF_B, NF_A03, NF_B)                                   \
    {                                                                                  \
        if ((T) + 2 < NT) STAGE((T) + 2);                                              \
        if ((T) + 2 < NT) { asm volatile("s_waitcnt vmcnt(4)" ::: "memory"); }         \
        else              { asm volatile("s_waitcnt vmcnt(0)" ::: "memory"); }         \
        __builtin_amdgcn_s_barrier();                                                  \
        __builtin_amdgcn_sched_barrier(0);                                             \
        const char* sa_ = (const char*)sA[(T) & 3];                                    \
        _Pragma("unroll")                                                              \
        for (int m = 0; m < 4; ++m)                                                    \
            a47[m] = *(const bf16x8*)(sa_ + ((((wm * 128 + (m + 4) * 16 + p) * 32 + q * 8) * 2) ^ axr)); \
        asm volatile("s_waitcnt lgkmcnt(4)" ::: "memory");                             \
        __builtin_amdgcn_sched_barrier(0);                                             \
        __builtin_amdgcn_s_setprio(1);                                                 \
        _Pragma("unroll")                                                              \
        for (int m = 0; m < 4; ++m)                                                    \
            _Pragma("unroll")                                                          \
            for (int n = 0; n < 4; ++n)                                                \
                acc[m][n] = __builtin_amdgcn_mfma_f32_16x16x32_bf16(CF_A03[m], CF_B[n], acc[m][n], 0, 0, 0); \
        __builtin_amdgcn_s_setprio(0);                                                 \
        asm volatile("s_waitcnt lgkmcnt(0)" ::: "memory");                             \
        __builtin_amdgcn_sched_barrier(0);                                             \
        if ((T) + 1 < NT) {                                                            \
            const char* sa1 = (const char*)sA[((T) + 1) & 3];                          \
            const char* sb1 = (const char*)sB[((T) + 1) & 3];                          \
            _Pragma("unroll")                                                          \
            for (int n = 0; n < 4; ++n)                                                \
                NF_B[n] = *(const bf16x8*)(sb1 + ((((wn * 64 + n * 16 + p) * 32 + q * 8) * 2) ^ axr)); \
            _Pragma("unroll")                                                          \
            for (int m = 0; m < 4; ++m)                                                \
                NF_A03[m] = *(const bf16x8*)(sa1 + ((((wm * 128 + m * 16 + p) * 32 + q * 8) * 2) ^ axr)); \
        }                                                                              \
        __builtin_amdgcn_sched_barrier(0);                                             \
        __builtin_amdgcn_s_setprio(1);                                                 \
        _Pragma("unroll")                                                              \
        for (int m = 0; m < 4; ++m)                                                    \
            _Pragma("unroll")                                                          \
            for (int n = 0; n < 4; ++n)                                                \
                acc[m + 4][n] = __builtin_amdgcn_mfma_f32_16x16x32_bf16(a47[m], CF_B[n], acc[m + 4][n], 0, 0, 0); \
        __builtin_amdgcn_s_setprio(0);                                                 \
        __builtin_amdgcn_sched_barrier(0);                                             \
    }

    for (int tt = 0; tt < NT; tt += 2) {
        TILE_BODY(tt,     a03x, bfx, a03y, bfy)   // tile tt   : consume x, prefetch y
        TILE_BODY(tt + 1, a03y, bfy, a03x, bfx)   // tile tt+1 : consume y, prefetch x
    }
    #undef TILE_BODY

    const int rowb = rowA0 + wm * 128;
    const int colb = rowB0 + wn * 64;
    #pragma unroll
    for (int m = 0; m < 8; ++m) {
        #pragma unroll
        for (int n = 0; n < 4; ++n) {
            int col = colb + n * 16 + p;
            float bv = bias ? bias[col] : 0.f;
            #pragma unroll
            for (int r = 0; r < 4; ++r) {
                int row = rowb + m * 16 + q * 4 + r;
                float v = acc[m][n][r] + bv;
                if (HASMIX) {
                    float pp = __shfl_xor(v, 1);       // partner col (uniform exec)
                    if (col >= 1024) {
                        int k = (col - 1024) >> 1;
                        float2 c = cmix[(row & 15) * 64 + k];
                        v = v * c.x + (((p & 1) == 0) ? -pp * c.y : pp * c.y);
                    }
                    if (col < ncols) Cout[(size_t)row * ldc + col] = (bf16)v;
                } else {
                    if (ACT) v = swishf(v);
                    Cout[(size_t)row * ldc + col] = (bf16)v;
                }
            }
        }
    }
}

// ---------------- 128^2 GEMM for the layer-2 analysis+mix step ----------------
__global__ __launch_bounds__(256)
void gemm_mix(const bf16* __restrict__ A, int lda,
              const bf16* __restrict__ Bt, int ldb,
              void* __restrict__ Cout, int ldc,
              const float2* __restrict__ cmix,
              int K) {
    __shared__ bf16 sA[128 * 64];
    __shared__ bf16 sB[128 * 64];
    const int tid = threadIdx.x;
    const int wave = tid >> 6;
    const int lane = tid & 63;
    const int wm = wave >> 1, wn = wave & 1;
    const int rowA0 = blockIdx.x * 128;

    f32x4 acc[4][4];
    #pragma unroll
    for (int m = 0; m < 4; ++m)
        #pragma unroll
        for (int n = 0; n < 4; ++n)
            acc[m][n] = f32x4{0.f, 0.f, 0.f, 0.f};

    const int srow = wave * 32 + (lane >> 3);
    const int scol = (lane & 7) * 8;
    const bf16* gA = A + (size_t)(rowA0 + srow) * lda + scol;
    const bf16* gB = Bt + (size_t)srow * ldb + scol;
    bf16* lA = &sA[(wave * 32) * 64];
    bf16* lB = &sB[(wave * 32) * 64];

    for (int k0 = 0; k0 < K; k0 += 64) {
        __syncthreads();
        #pragma unroll
        for (int i = 0; i < 4; ++i) {
            gl_lds16(gA + (size_t)i * 8 * lda + k0, lA + i * 8 * 64);
            gl_lds16(gB + (size_t)i * 8 * ldb + k0, lB + i * 8 * 64);
        }
        __syncthreads();
        #pragma unroll
        for (int kk = 0; kk < 64; kk += 32) {
            bf16x8 af[4], bfr[4];
            #pragma unroll
            for (int m = 0; m < 4; ++m)
                af[m] = *(const bf16x8*)&sA[(wm * 64 + m * 16 + (lane & 15)) * 64 + kk + ((lane >> 4) * 8)];
            #pragma unroll
            for (int n = 0; n < 4; ++n)
                bfr[n] = *(const bf16x8*)&sB[(wn * 64 + n * 16 + (lane & 15)) * 64 + kk + ((lane >> 4) * 8)];
            #pragma unroll
            for (int m = 0; m < 4; ++m)
                #pragma unroll
                for (int n = 0; n < 4; ++n)
                    acc[m][n] = __builtin_amdgcn_mfma_f32_16x16x32_bf16(af[m], bfr[n], acc[m][n], 0, 0, 0);
        }
    }

    const int rowb = rowA0 + wm * 64;
    #pragma unroll
    for (int m = 0; m < 4; ++m) {
        #pragma unroll
        for (int n = 0; n < 4; ++n) {
            int col = wn * 64 + n * 16 + (lane & 15);
            int k = col >> 1;
            #pragma unroll
            for (int r = 0; r < 4; ++r) {
                float v = acc[m][n][r];
                float pp = __shfl_xor(v, 1);
                int row = rowb + m * 16 + (lane >> 4) * 4 + r;
                float2 c = cmix[(row & 15) * 64 + k];
                float val = v * c.x + (((lane & 1) == 0) ? -pp * c.y : pp * c.y);
                ((bf16*)Cout)[(size_t)row * ldc + col] = (bf16)val;
            }
        }
    }
}

// ---------------- fused fc1 + swish + fc2 (bf16) ----------------
__global__ __launch_bounds__(256) void fc_fused(const bf16* __restrict__ H,
                                                const float* __restrict__ w1,
                                                const float* __restrict__ b1,
                                                const float* __restrict__ w2,
                                                const float* __restrict__ b2,
                                                float* __restrict__ out) {
    __shared__ bf16 sw2[8][2048];
    __shared__ bf16 ss[2048];
    int tid = threadIdx.x;
    for (int i = tid * 4; i < 8 * 2048; i += 1024) {
        float4 v = *(const float4*)(w2 + i);
        bf16x4 b = {(bf16)v.x, (bf16)v.y, (bf16)v.z, (bf16)v.w};
        *(bf16x4*)&sw2[0][i] = b;
    }

    float wv[16];
    const float4* w1p = (const float4*)(w1 + tid * 16);
    *(float4*)&wv[0]  = w1p[0];
    *(float4*)&wv[4]  = w1p[1];
    *(float4*)&wv[8]  = w1p[2];
    *(float4*)&wv[12] = w1p[3];
    float bb[8];
    const float4* b1p = (const float4*)(b1 + tid * 8);
    *(float4*)&bb[0] = b1p[0];
    *(float4*)&bb[4] = b1p[1];
    __syncthreads();

    for (int r = 0; r < 16; ++r) {
        int n = blockIdx.x * 16 + r;
        bf16x4 hv = *(const bf16x4*)(H + (size_t)n * 1024 + tid * 4);
        float hh[4] = {(float)hv[0], (float)hv[1], (float)hv[2], (float)hv[3]};
        bf16x8 sb;
        #pragma unroll
        for (int jj = 0; jj < 8; ++jj) {
            float h0 = hh[(jj >> 2) * 2];
            float h1 = hh[(jj >> 2) * 2 + 1];
            float t = h0 * wv[2 * jj] + h1 * wv[2 * jj + 1] + bb[jj];
            sb[jj] = (bf16)swishf(t);
        }
        *(bf16x8*)&ss[tid * 8] = sb;
        __syncthreads();
        int o8 = tid >> 5, l5 = tid & 31;
        float p = 0.f;
        #pragma unroll
        for (int i = 0; i < 16; ++i) {
            bf16x4 a = *(const bf16x4*)&ss[4 * l5 + 128 * i];
            bf16x4 b = *(const bf16x4*)&sw2[o8][4 * l5 + 128 * i];
            p += (float)a[0] * (float)b[0] + (float)a[1] * (float)b[1]
               + (float)a[2] * (float)b[2] + (float)a[3] * (float)b[3];
        }
        #pragma unroll
        for (int msk = 1; msk < 32; msk <<= 1) p += __shfl_xor(p, msk);
        if (l5 == 0) out[(size_t)n * 8 + o8] = p + b2[o8];
        __syncthreads();
    }
}

// ---------------- launch ----------------

extern "C" void kernel_launch(void* const* d_in, const int* in_sizes, int n_in,
                              void* d_out, int out_size, void* d_ws, size_t ws_size,
                              hipStream_t stream) {
    const float* x     = (const float*)d_in[0];
    const float* codes = (const float*)d_in[1];
    const float* p_w   = (const float*)d_in[2];
    const float* p_b   = (const float*)d_in[3];
    const float* com0  = (const float*)d_in[4];
    const float* code0 = (const float*)d_in[5];
    const float* filt0 = (const float*)d_in[6];
    const float* com1  = (const float*)d_in[7];
    const float* code1 = (const float*)d_in[8];
    const float* filt1 = (const float*)d_in[9];
    const float* w0_w  = (const float*)d_in[10];
    const float* w0_b  = (const float*)d_in[11];
    const float* w1_w  = (const float*)d_in[12];
    const float* w1_b  = (const float*)d_in[13];
    const float* fc1w  = (const float*)d_in[14];
    const float* fc1b  = (const float*)d_in[15];
    const float* fc2w  = (const float*)d_in[16];
    const float* fc2b  = (const float*)d_in[17];
    float* out = (float*)d_out;

    // fixed weight region (~7.1 MB)
    char* ws = (char*)d_ws;
    bf16*  WP   = (bf16*)(ws + 0);               // 1,310,720
    bf16*  B0   = (bf16*)(ws + 1310720);         // 2,359,296
    bf16*  B1   = (bf16*)(ws + 3670016);         // 2,359,296
    bf16*  Fbb  = (bf16*)(ws + 6029312);         // 262,144
    float* Fb32 = (float*)(ws + 6291456);        // 524,288
    float* G32  = (float*)(ws + 6815744);        // 262,144
    float* bias1= (float*)(ws + 7077888);        // 5,120
    float2* cm0 = (float2*)(ws + 7083008);       // 8,192
    float2* cm1 = (float2*)(ws + 7091200);       // 8,192
    const size_t CB = 7099392;

    const size_t PER_ROW = 2048 + 2304 + 2304;   // 6656
    long rmax = 0;
    if (ws_size > CB) rmax = (long)((ws_size - CB) / PER_ROW) / 256 * 256;
    if (rmax > N_ROWS) rmax = N_ROWS;
    if (rmax < 256) {
        hipMemsetAsync(d_out, 0, (size_t)out_size * sizeof(float), stream);
        return;
    }
    const int R = (int)rmax;

    build_cmix<<<4, 256, 0, stream>>>(codes, com0, code0, filt0, cm0);
    build_cmix<<<4, 256, 0, stream>>>(codes, com1, code1, filt1, cm1);
    build_fb2<<<512, 256, 0, stream>>>(Fb32, Fbb);
    build_bcat<<<4608, 256, 0, stream>>>(w0_w, B0);
    build_bcat<<<4608, 256, 0, stream>>>(w1_w, B1);
    build_g<<<dim3(2, 128), 256, 0, stream>>>(Fb32, p_w, G32);
    build_bias1a<<<256, 256, 0, stream>>>(p_w, p_b, bias1);
    build_bias1b<<<32, 256, 0, stream>>>(Fb32, bias1);
    build_wp<<<2560, 256, 0, stream>>>(p_w, G32, WP);

    char* cb = ws + CB;
    for (int row0 = 0; row0 < N_ROWS; row0 += R) {
        const int r = (N_ROWS - row0 < R) ? (N_ROWS - row0) : R;   // multiple of 256
        bf16*  A0  = (bf16*)cb;
        bf16*  H3b = (bf16*)cb;                                    // reuses A0 region
        bf16*  A1  = (bf16*)(cb + (size_t)R * 2048);
        bf16*  A2  = (bf16*)(cb + (size_t)R * 2048 + (size_t)R * 2304);
        const int NX = r / 256;

        convert_x<<<r / 4, 256, 0, stream>>>(x + (size_t)row0 * 512, A0);

        // A1cat[:,0:1024] = A0@p_w[:, :512]^T + bias1; [:,1024:1152] = mix(A0@G^T + b1B)
        gemm256<0, 1><<<NX * 5, 512, 0, stream>>>(
            A0, 512, WP, 512, bias1, A1, 1152, cm0, 1152, 512, NX, 5);
        // A2cat[:,0:1024] = swish(A1cat @ Bcat0^T + w0_b)
        gemm256<1, 0><<<NX * 4, 512, 0, stream>>>(
            A1, 1152, B0, 1152, w0_b, A2, 1152, nullptr, 1024, 1152, NX, 4);
        // A2cat[:,1024:1152] = mix(A2[:,0:1024] @ Fb^T)
        gemm_mix<<<dim3(r / 128, 1), 256, 0, stream>>>(
            A2, 1152, Fbb, 1024, (void*)(A2 + 1024), 1152, cm1, 1024);
        // H3 = A2cat @ Bcat1^T + w1_b (bf16)
        gemm256<0, 0><<<NX * 4, 512, 0, stream>>>(
            A2, 1152, B1, 1152, w1_b, H3b, 1024, nullptr, 1024, 1152, NX, 4);
        // out = fc2(swish(fc1(H3)))
        fc_fused<<<r / 16, 256, 0, stream>>>(H3b, fc1w, fc1b, fc2w, fc2b, out + (size_t)row0 * 8);
    }
}